// Round 4
// baseline (241.990 us; speedup 1.0000x reference)
//
#include <hip/hip_runtime.h>
#include <math.h>

#define N_NODES_C 100000
#define DIM_C     128
#define M_SEL_C   4096
#define N_POS_C   32
#define N_NEG_C   256
#define QSCALE    (2.0f / 255.0f)   // |z_a - z_b| = QSCALE * |q_a - q_b|

__device__ __forceinline__ float wsum64(float v) {
#pragma unroll
    for (int o = 32; o; o >>= 1) v += __shfl_xor(v, o, 64);
    return v;
}
// sum within each 32-lane half
__device__ __forceinline__ float hsum32(float v) {
#pragma unroll
    for (int o = 1; o < 32; o <<= 1) v += __shfl_xor(v, o, 64);
    return v;
}
// int sum within each 8-lane subgroup (all 8 lanes end with the total)
__device__ __forceinline__ int gsum8(int v) {
#pragma unroll
    for (int o = 1; o < 8; o <<= 1) v += __shfl_xor(v, o, 64);
    return v;
}

// v_sad_u8: per-byte |a-b| summed + acc (exact, int domain)
__device__ __forceinline__ unsigned sad8(unsigned a, unsigned b, unsigned acc) {
    unsigned d;
    asm volatile("v_sad_u8 %0, %1, %2, %3" : "=v"(d) : "v"(a), "v"(b), "v"(acc));
    return d;
}
__device__ __forceinline__ int sad16B(uint4 a, uint4 b) {
    return (int)sad8(a.w, b.w, sad8(a.z, b.z, sad8(a.y, b.y, sad8(a.x, b.x, 0u))));
}

__global__ void k_zero(float* out, int n) {
    int i = blockIdx.x * blockDim.x + threadIdx.x;
    if (i < n) out[i] = 0.0f;
}

// Fused: sigma = 1/(1+e^-x); table Q[row][d] = round(255*sigma) as uint8;
// L_deg = mean((Z@W_d - deg)^2) with z = 2*sigma-1.
__global__ __launch_bounds__(256) void k_z_deg(
    const float* __restrict__ P, const float* __restrict__ Wd,
    const float* __restrict__ deg, unsigned* __restrict__ Q,
    float* __restrict__ out)
{
    const int lane = threadIdx.x & 63;
    const int sl   = lane & 31;
    const int hi   = lane >> 5;
    const int wv   = threadIdx.x >> 6;
    const int gw   = blockIdx.x * 4 + wv;
    const int nw   = gridDim.x * 4;
    const float4 w = *(const float4*)(Wd + 4 * sl);
    float acc = 0.0f;
    for (int pr = gw; pr < N_NODES_C / 2; pr += nw) {
        const int row = 2 * pr + hi;
        float4 p = *(const float4*)(P + (size_t)row * DIM_C + 4 * sl);
        float r0 = __fdividef(255.0f, 1.0f + __expf(-p.x));
        float r1 = __fdividef(255.0f, 1.0f + __expf(-p.y));
        float r2 = __fdividef(255.0f, 1.0f + __expf(-p.z));
        float r3 = __fdividef(255.0f, 1.0f + __expf(-p.w));
        unsigned q = __float2uint_rn(r0) | (__float2uint_rn(r1) << 8) |
                     (__float2uint_rn(r2) << 16) | (__float2uint_rn(r3) << 24);
        Q[(size_t)row * (DIM_C / 4) + sl] = q;
        float z0 = fmaf(r0, QSCALE, -1.0f), z1 = fmaf(r1, QSCALE, -1.0f);
        float z2 = fmaf(r2, QSCALE, -1.0f), z3 = fmaf(r3, QSCALE, -1.0f);
        float d4 = fmaf(z0, w.x, fmaf(z1, w.y, fmaf(z2, w.z, z3 * w.w)));
        d4 = hsum32(d4);
        if (sl == 0) { float d = d4 - deg[row]; acc = fmaf(d, d, acc); }
    }
    __shared__ float part[4];
    float a = wsum64(acc);
    if (lane == 0) part[wv] = a;
    __syncthreads();
    if (threadIdx.x == 0)
        atomicAdd(out + 2, (part[0] + part[1] + part[2] + part[3]) * (1.0f / N_NODES_C));
}

// Fused contrast, wave-per-node: 2048 blocks x 4 waves = 8192 (m,sel) pairs.
// Each wave: 8 lanes per row (uint4 = 16 B/lane), 8 rows per batch, prefetch
// depth 8, online LSE in-register, zero main-loop barriers.
__global__ __launch_bounds__(256, 6) void k_contrast(
    const unsigned* __restrict__ Q,
    const int* __restrict__ nodes,
    const int* __restrict__ pos_a, const int* __restrict__ neg_a,
    const int* __restrict__ pos_b, const int* __restrict__ neg_b,
    float* __restrict__ out)
{
    const int tid  = threadIdx.x;
    const int wv   = tid >> 6;
    const int lane = tid & 63;
    const int l8   = lane & 7;    // lane within row
    const int g    = lane >> 3;   // subgroup = row within batch

    const int id   = blockIdx.x * 4 + wv;       // 0..8191
    const int sel  = id >> 12;
    const int m    = id & (M_SEL_C - 1);
    const int* __restrict__ pos_idx = sel ? pos_b : pos_a;
    const int* __restrict__ neg_idx = sel ? neg_b : neg_a;

    __shared__ int sNeg[4][N_NEG_C];
    __shared__ int sPos[4][N_POS_C];

    // stage indices (coalesced int4)
    ((int4*)sNeg[wv])[lane] = ((const int4*)(neg_idx + m * N_NEG_C))[lane];
    if (lane < N_POS_C / 4)
        ((int4*)sPos[wv])[lane] = ((const int4*)(pos_idx + m * N_POS_C))[lane];
    const int node = nodes[m];
    const uint4* __restrict__ Q4 = (const uint4*)Q;   // row = 8 uint4
    uint4 c = Q4[((unsigned)node << 3) + l8];
    __syncthreads();   // one barrier; waves are independent afterwards

    // ---- positives: 32 rows = 4 batches of 8, fully prefetched ----
    float ps = 0.0f;
    {
        int pn[4];
#pragma unroll
        for (int t = 0; t < 4; ++t) pn[t] = sPos[wv][t * 8 + g];
        uint4 pb[4];
#pragma unroll
        for (int t = 0; t < 4; ++t) pb[t] = Q4[((unsigned)pn[t] << 3) + l8];
#pragma unroll
        for (int t = 0; t < 4; ++t) ps += (float)gsum8(sad16B(c, pb[t]));
    }

    // ---- negatives: 256 rows = 32 batches of 8, prefetch depth 8 ----
    float mx = -1e30f, sm = 0.0f;
#pragma unroll 1
    for (int tt = 0; tt < 32; tt += 8) {
        int nn[8];
#pragma unroll
        for (int u = 0; u < 8; ++u) nn[u] = sNeg[wv][(tt + u) * 8 + g];
        uint4 nb[8];
#pragma unroll
        for (int u = 0; u < 8; ++u) nb[u] = Q4[((unsigned)nn[u] << 3) + l8];
#pragma unroll
        for (int u = 0; u < 8; ++u) {
            float v = (float)gsum8(sad16B(c, nb[u])) * QSCALE;
            float nm = fmaxf(mx, v);
            sm = fmaf(sm, __expf(mx - nm), __expf(v - nm));
            mx = nm;
        }
    }

    // ---- merge the 8 subgroup streams (lanes already uniform within subgroup)
#pragma unroll
    for (int o = 8; o < 64; o <<= 1) {
        float om = __shfl_xor(mx, o, 64);
        float os = __shfl_xor(sm, o, 64);
        float nm = fmaxf(mx, om);
        sm = fmaf(sm, __expf(mx - nm), os * __expf(om - nm));
        mx = nm;
        ps += __shfl_xor(ps, o, 64);
    }

    if (lane == 0) {
        float lse = mx + __logf(sm);
        float pm  = ps * QSCALE * (1.0f / N_POS_C);
        atomicAdd(out + sel, lse - pm);
    }
}

extern "C" void kernel_launch(void* const* d_in, const int* in_sizes, int n_in,
                              void* d_out, int out_size, void* d_ws, size_t ws_size,
                              hipStream_t stream) {
    const float* P    = (const float*)d_in[0];
    const float* Wd   = (const float*)d_in[1];
    const float* deg  = (const float*)d_in[2];
    const int* nodes  = (const int*)d_in[3];
    const int* pos_i  = (const int*)d_in[4];
    const int* neg_i  = (const int*)d_in[5];
    const int* dpos_i = (const int*)d_in[6];
    const int* dneg_i = (const int*)d_in[7];
    float* out  = (float*)d_out;
    unsigned* Q = (unsigned*)d_ws;   // 12.8 MB uint8 table

    k_zero<<<1, 256, 0, stream>>>(out, out_size);
    k_z_deg<<<2048, 256, 0, stream>>>(P, Wd, deg, Q, out);
    k_contrast<<<2048, 256, 0, stream>>>(
        Q, nodes, pos_i, neg_i, dpos_i, dneg_i, out);
}

// Round 5
// 238.689 us; speedup vs baseline: 1.0138x; 1.0138x over previous
//
#include <hip/hip_runtime.h>
#include <math.h>

#define N_NODES_C 100000
#define DIM_C     128
#define M_SEL_C   4096
#define N_POS_C   32
#define N_NEG_C   256
#define QS4       (2.0f / 15.0f)   // |z_a - z_b| = QS4 * |q4_a - q4_b|

__device__ __forceinline__ float wsum64(float v) {
#pragma unroll
    for (int o = 32; o; o >>= 1) v += __shfl_xor(v, o, 64);
    return v;
}
__device__ __forceinline__ float hsum32(float v) {
#pragma unroll
    for (int o = 1; o < 32; o <<= 1) v += __shfl_xor(v, o, 64);
    return v;
}
// int sum within each 4-lane subgroup
__device__ __forceinline__ int gsum4(int v) {
    v += __shfl_xor(v, 1, 64);
    v += __shfl_xor(v, 2, 64);
    return v;
}

// v_sad_u8: per-byte |a-b| summed + acc (exact, int domain)
__device__ __forceinline__ unsigned sad8(unsigned a, unsigned b, unsigned acc) {
    unsigned d;
    asm volatile("v_sad_u8 %0, %1, %2, %3" : "=v"(d) : "v"(a), "v"(b), "v"(acc));
    return d;
}

// SAD of one 16-byte fragment (32 nibble-packed dims) vs pre-split center
__device__ __forceinline__ int sadrow4(uint4 b, const unsigned* cl, const unsigned* ch) {
    const unsigned M = 0x0F0F0F0Fu;
    unsigned s = 0;
    s = sad8(b.x & M, cl[0], s); s = sad8((b.x >> 4) & M, ch[0], s);
    s = sad8(b.y & M, cl[1], s); s = sad8((b.y >> 4) & M, ch[1], s);
    s = sad8(b.z & M, cl[2], s); s = sad8((b.z >> 4) & M, ch[2], s);
    s = sad8(b.w & M, cl[3], s); s = sad8((b.w >> 4) & M, ch[3], s);
    return (int)s;
}

// Fused: sigma = 1/(1+e^-x); Q4 table row = 64 B, byte b = dim 2b (lo) | dim 2b+1 (hi);
// L_deg = mean((Z@W_d - deg)^2) with z = 2*sigma-1 (full precision).
__global__ __launch_bounds__(256) void k_z_deg(
    const float* __restrict__ P, const float* __restrict__ Wd,
    const float* __restrict__ deg, unsigned short* __restrict__ Qh,
    float* __restrict__ out)
{
    const int lane = threadIdx.x & 63;
    const int sl   = lane & 31;
    const int hi   = lane >> 5;
    const int wv   = threadIdx.x >> 6;
    const int gw   = blockIdx.x * 4 + wv;
    const int nw   = gridDim.x * 4;
    const float4 w = *(const float4*)(Wd + 4 * sl);
    float acc = 0.0f;
    for (int pr = gw; pr < N_NODES_C / 2; pr += nw) {
        const int row = 2 * pr + hi;
        float4 p = *(const float4*)(P + (size_t)row * DIM_C + 4 * sl);
        // r = 15*sigma in [0,15]
        float r0 = __fdividef(15.0f, 1.0f + __expf(-p.x));
        float r1 = __fdividef(15.0f, 1.0f + __expf(-p.y));
        float r2 = __fdividef(15.0f, 1.0f + __expf(-p.z));
        float r3 = __fdividef(15.0f, 1.0f + __expf(-p.w));
        unsigned q = __float2uint_rn(r0) | (__float2uint_rn(r1) << 4) |
                     (__float2uint_rn(r2) << 8) | (__float2uint_rn(r3) << 12);
        Qh[(size_t)row * (DIM_C / 4) + sl] = (unsigned short)q;
        float z0 = fmaf(r0, QS4, -1.0f), z1 = fmaf(r1, QS4, -1.0f);
        float z2 = fmaf(r2, QS4, -1.0f), z3 = fmaf(r3, QS4, -1.0f);
        float d4 = fmaf(z0, w.x, fmaf(z1, w.y, fmaf(z2, w.z, z3 * w.w)));
        d4 = hsum32(d4);
        if (sl == 0) { float d = d4 - deg[row]; acc = fmaf(d, d, acc); }
    }
    __shared__ float part[4];
    float a = wsum64(acc);
    if (lane == 0) part[wv] = a;
    __syncthreads();
    if (threadIdx.x == 0)
        atomicAdd(out + 2, (part[0] + part[1] + part[2] + part[3]) * (1.0f / N_NODES_C));
}

// Fused contrast on the 4-bit table. Wave-per-node: 2048 blocks x 4 waves =
// 8192 (m,sel) pairs. 4 lanes per 64-B row (uint4/lane), 16 rows per wave-load,
// prefetch depth 8, online LSE in-register, zero main-loop barriers.
__global__ __launch_bounds__(256, 6) void k_contrast(
    const uint4* __restrict__ Q4,    // row = 4 uint4
    const int* __restrict__ nodes,
    const int* __restrict__ pos_a, const int* __restrict__ neg_a,
    const int* __restrict__ pos_b, const int* __restrict__ neg_b,
    float* __restrict__ out)
{
    const int tid  = threadIdx.x;
    const int wv   = tid >> 6;
    const int lane = tid & 63;
    const int l4   = lane & 3;    // lane within row (16 B each)
    const int g    = lane >> 2;   // subgroup = row slot 0..15

    const int id   = blockIdx.x * 4 + wv;       // 0..8191
    const int sel  = id >> 12;
    const int m    = id & (M_SEL_C - 1);
    const int* __restrict__ pos_idx = sel ? pos_b : pos_a;
    const int* __restrict__ neg_idx = sel ? neg_b : neg_a;

    __shared__ int sNeg[4][N_NEG_C];
    __shared__ int sPos[4][N_POS_C];

    ((int4*)sNeg[wv])[lane] = ((const int4*)(neg_idx + m * N_NEG_C))[lane];
    if (lane < N_POS_C / 4)
        ((int4*)sPos[wv])[lane] = ((const int4*)(pos_idx + m * N_POS_C))[lane];
    const int node = nodes[m];
    uint4 c = Q4[((unsigned)node << 2) + l4];
    const unsigned M = 0x0F0F0F0Fu;
    unsigned cl[4] = { c.x & M, c.y & M, c.z & M, c.w & M };
    unsigned ch[4] = { (c.x >> 4) & M, (c.y >> 4) & M, (c.z >> 4) & M, (c.w >> 4) & M };
    __syncthreads();   // waves independent afterwards

    // ---- positives: 32 rows = 2 wave-loads ----
    int pn0 = sPos[wv][g], pn1 = sPos[wv][16 + g];
    uint4 pb0 = Q4[((unsigned)pn0 << 2) + l4];
    uint4 pb1 = Q4[((unsigned)pn1 << 2) + l4];
    int psi = sadrow4(pb0, cl, ch) + sadrow4(pb1, cl, ch);   // per-lane partial

    // ---- negatives: 256 rows = 16 wave-loads, 2 rounds of 8 ----
    float mx = -1e30f, sm = 0.0f;
#pragma unroll 1
    for (int r = 0; r < 2; ++r) {
        int nn[8];
#pragma unroll
        for (int u = 0; u < 8; ++u) nn[u] = sNeg[wv][r * 128 + u * 16 + g];
        uint4 nb[8];
#pragma unroll
        for (int u = 0; u < 8; ++u) nb[u] = Q4[((unsigned)nn[u] << 2) + l4];
#pragma unroll
        for (int u = 0; u < 8; ++u) {
            int s = gsum4(sadrow4(nb[u], cl, ch));   // row total on all 4 lanes
            float v = (float)s * QS4;
            float nm = fmaxf(mx, v);
            sm = fmaf(sm, __expf(mx - nm), __expf(v - nm));
            mx = nm;
        }
    }

    // ---- merge: LSE across 16 subgroup streams, pos across all 64 lanes ----
    float ps = (float)psi;
#pragma unroll
    for (int o = 1; o < 4; o <<= 1) ps += __shfl_xor(ps, o, 64);
#pragma unroll
    for (int o = 4; o < 64; o <<= 1) {
        float om = __shfl_xor(mx, o, 64);
        float os = __shfl_xor(sm, o, 64);
        float nm = fmaxf(mx, om);
        sm = fmaf(sm, __expf(mx - nm), os * __expf(om - nm));
        mx = nm;
        ps += __shfl_xor(ps, o, 64);
    }

    if (lane == 0) {
        float lse = mx + __logf(sm);
        float pm  = ps * QS4 * (1.0f / N_POS_C);
        atomicAdd(out + sel, lse - pm);
    }
}

extern "C" void kernel_launch(void* const* d_in, const int* in_sizes, int n_in,
                              void* d_out, int out_size, void* d_ws, size_t ws_size,
                              hipStream_t stream) {
    const float* P    = (const float*)d_in[0];
    const float* Wd   = (const float*)d_in[1];
    const float* deg  = (const float*)d_in[2];
    const int* nodes  = (const int*)d_in[3];
    const int* pos_i  = (const int*)d_in[4];
    const int* neg_i  = (const int*)d_in[5];
    const int* dpos_i = (const int*)d_in[6];
    const int* dneg_i = (const int*)d_in[7];
    float* out = (float*)d_out;
    unsigned short* Qh = (unsigned short*)d_ws;   // 100000*64 B = 6.4 MB

    hipMemsetAsync(out, 0, (size_t)out_size * sizeof(float), stream);
    k_z_deg<<<2048, 256, 0, stream>>>(P, Wd, deg, Qh, out);
    k_contrast<<<2048, 256, 0, stream>>>(
        (const uint4*)Qh, nodes, pos_i, neg_i, dpos_i, dneg_i, out);
}